// Round 5
// baseline (154.992 us; speedup 1.0000x reference)
//
#include <hip/hip_runtime.h>
#include <math.h>

typedef _Float16 f16;
typedef _Float16 half4_t __attribute__((ext_vector_type(4)));
typedef _Float16 half8_t __attribute__((ext_vector_type(8)));
typedef float floatx4 __attribute__((ext_vector_type(4)));

#define LDATA_OFF_BYTES 86016  // after W1t(16384B) + W2t(32768B) + W3t(36864B)

// ------------------------------------------------------------------
// Kernel P: repack weights fp32 -> f16, transposed [col][k] so B-operand
// fragments (k-chunks of 8) are contiguous 16B loads.
// ------------------------------------------------------------------
__global__ __launch_bounds__(256) void prep_weights(
    const float* __restrict__ W1, const float* __restrict__ W2,
    const float* __restrict__ W3, f16* __restrict__ wt) {
  int t = blockIdx.x * 256 + threadIdx.x;
  if (t < 8192) {                       // W1t [128][64]
    int c = t >> 6, k = t & 63;
    wt[t] = (f16)W1[k * 128 + c];
  } else if (t < 24576) {               // W2t [128][128]
    int u = t - 8192;
    int c = u >> 7, k = u & 127;
    wt[t] = (f16)W2[k * 128 + c];
  } else if (t < 43008) {               // W3t [144][128], cols 136..143 zero
    int u = t - 24576;
    int c = u >> 7, k = u & 127;
    wt[t] = (f16)((c < 136) ? W3[k * 136 + c] : 0.0f);
  }
}

// fast tanh: tanh(x) = 1 - 2/(e^{2x}+1)
__device__ __forceinline__ float fast_tanh(float v) {
  float e = __builtin_amdgcn_exp2f(v * 2.885390081777926814f);  // 2*log2(e)
  return 1.0f - 2.0f * __builtin_amdgcn_rcpf(e + 1.0f);
}

// ------------------------------------------------------------------
// Kernel M: fused 3-layer MLP, column-parallel. Block = 256 thr = 4 waves,
// 16 batch rows per BLOCK (not per wave); each wave computes a 32-column
// slice of every layer -> 16384 waves total (16/SIMD), short serial chains.
// Layer handoff via double-buffered LDS + __syncthreads.
// ------------------------------------------------------------------
__global__ __launch_bounds__(256) void mlp_kernel(
    const float* __restrict__ x, const float* __restrict__ b1,
    const float* __restrict__ b2v, const float* __restrict__ b3,
    const f16* __restrict__ wt, f16* __restrict__ ldata) {
  __shared__ f16 hb[2][16][136];
  const int tid = threadIdx.x;
  const int wave = tid >> 6;
  const int lane = tid & 63;
  const int cl = lane & 15;  // A-row / C-col index
  const int q = lane >> 4;   // quad: k-chunk / C-row-group
  const int r0 = blockIdx.x * 16;

  const f16* w1t = wt;           // [128][64]
  const f16* w2t = wt + 8192;    // [128][128]
  const f16* w3t = wt + 24576;   // [144][128]

  // ---- Layer 1: [16x64] @ [64x128], this wave: cols 32*wave..32*wave+31 ----
  half8_t a0, a1;
  {
    const float* xr = x + (size_t)(r0 + cl) * 64 + q * 8;
    floatx4 v0 = *(const floatx4*)(xr);
    floatx4 v1 = *(const floatx4*)(xr + 4);
    floatx4 v2 = *(const floatx4*)(xr + 32);
    floatx4 v3 = *(const floatx4*)(xr + 36);
#pragma unroll
    for (int i = 0; i < 4; ++i) {
      a0[i] = (f16)v0[i]; a0[i + 4] = (f16)v1[i];
      a1[i] = (f16)v2[i]; a1[i + 4] = (f16)v3[i];
    }
  }
#pragma unroll
  for (int t = 0; t < 2; ++t) {
    int c = (wave * 2 + t) * 16 + cl;
    half8_t w0 = *(const half8_t*)(w1t + c * 64 + q * 8);
    half8_t w1v = *(const half8_t*)(w1t + c * 64 + 32 + q * 8);
    floatx4 acc = {0.f, 0.f, 0.f, 0.f};
    acc = __builtin_amdgcn_mfma_f32_16x16x32_f16(a0, w0, acc, 0, 0, 0);
    acc = __builtin_amdgcn_mfma_f32_16x16x32_f16(a1, w1v, acc, 0, 0, 0);
    float bias = b1[c];
#pragma unroll
    for (int i = 0; i < 4; ++i) {
      float v = acc[i] + bias;
      v = v > 0.f ? v : 0.01f * v;  // LeakyReLU
      hb[0][q * 4 + i][c] = (f16)v;
    }
  }
  __syncthreads();

  // ---- Layer 2: [16x128] @ [128x128], cols 32*wave..32*wave+31 ----
  half8_t ha[4];
#pragma unroll
  for (int ks = 0; ks < 4; ++ks)
    ha[ks] = *(const half8_t*)(&hb[0][cl][ks * 32 + q * 8]);
#pragma unroll
  for (int t = 0; t < 2; ++t) {
    int c = (wave * 2 + t) * 16 + cl;
    floatx4 acc = {0.f, 0.f, 0.f, 0.f};
#pragma unroll
    for (int ks = 0; ks < 4; ++ks) {
      half8_t wv = *(const half8_t*)(w2t + c * 128 + ks * 32 + q * 8);
      acc = __builtin_amdgcn_mfma_f32_16x16x32_f16(ha[ks], wv, acc, 0, 0, 0);
    }
    float bias = b2v[c];
#pragma unroll
    for (int i = 0; i < 4; ++i) {
      float v = acc[i] + bias;
      v = v > 0.f ? v : 0.01f * v;
      hb[1][q * 4 + i][c] = (f16)v;
    }
  }
  __syncthreads();

  // ---- Layer 3: [16x128] @ [128x136] + tanh; tiles {w, w+4}, wave3 adds 8 ----
#pragma unroll
  for (int ks = 0; ks < 4; ++ks)
    ha[ks] = *(const half8_t*)(&hb[1][cl][ks * 32 + q * 8]);
  const int ntile = (wave == 3) ? 3 : 2;
#pragma unroll
  for (int t = 0; t < 3; ++t) {
    if (t >= ntile) break;
    int c8 = (t == 2) ? 8 : (wave + t * 4);
    int c = c8 * 16 + cl;  // 0..143
    floatx4 acc = {0.f, 0.f, 0.f, 0.f};
#pragma unroll
    for (int ks = 0; ks < 4; ++ks) {
      half8_t wv = *(const half8_t*)(w3t + c * 128 + ks * 32 + q * 8);
      acc = __builtin_amdgcn_mfma_f32_16x16x32_f16(ha[ks], wv, acc, 0, 0, 0);
    }
    if (c < 136) {
      float bias = b3[c];
#pragma unroll
      for (int i = 0; i < 4; ++i)
        ldata[(size_t)(r0 + q * 4 + i) * 136 + c] = (f16)fast_tanh(acc[i] + bias);
    }
  }
}

// ---- DPP wave64 sum: row_shr 1/2/4/8 then row_bcast 15/31; total in lane 63.
template <int CTRL>
__device__ __forceinline__ float dpp_add(float v) {
  int t = __builtin_amdgcn_update_dpp(0, __builtin_bit_cast(int, v), CTRL,
                                      0xf, 0xf, true);
  return v + __builtin_bit_cast(float, t);
}
__device__ __forceinline__ float wsum(float v) {
  v = dpp_add<0x111>(v);  // row_shr:1
  v = dpp_add<0x112>(v);  // row_shr:2
  v = dpp_add<0x114>(v);  // row_shr:4
  v = dpp_add<0x118>(v);  // row_shr:8
  v = dpp_add<0x142>(v);  // row_bcast:15
  v = dpp_add<0x143>(v);  // row_bcast:31
  return __builtin_bit_cast(
      float, __builtin_amdgcn_readlane(__builtin_bit_cast(int, v), 63));
}

// round floatx4 -> half4 via packed RTZ converts
__device__ __forceinline__ half4_t to_h(floatx4 v) {
  auto p0 = __builtin_amdgcn_cvt_pkrtz(v[0], v[1]);
  auto p1 = __builtin_amdgcn_cvt_pkrtz(v[2], v[3]);
  half4_t h;
  h[0] = p0[0]; h[1] = p0[1]; h[2] = p1[0]; h[3] = p1[1];
  return h;
}

// ------------------------------------------------------------------
// p = expm(B - m I), m = trace/16. Canonical symmetric fragment layout:
// lane value_i = X[l&15][4*(l>>4)+i] is simultaneously a valid A, B and C/D
// layout for v_mfma_f32_16x16x16_f16 (polynomials of a symmetric matrix stay
// symmetric -> zero cross-lane data movement). Degree-4 Paterson-Stockmeyer,
// spectral bound theta <= 0.354 via Frobenius power-of-2 scaling.
// ------------------------------------------------------------------
__device__ __forceinline__ floatx4 expm_c(floatx4 b, floatx4 I4, float& m) {
  float s2 = wsum(b[0] * b[0] + b[1] * b[1] + b[2] * b[2] + b[3] * b[3]);
  float td = wsum(I4[0] * b[0] + I4[1] * b[1] + I4[2] * b[2] + I4[3] * b[3]);
  m = td * 0.0625f;
  float fr2 = fmaxf(s2 - td * m, 1e-30f);  // ||B - mI||_F^2
  int e2 = (int)(__builtin_bit_cast(unsigned, fr2) >> 23) - 127;
  int s = (e2 + 5) >> 1;  // guarantees 2^-s * fr <= 2^-1.5 = 0.354
  s = s < 0 ? 0 : (s > 12 ? 12 : s);
  s = __builtin_amdgcn_readfirstlane(s);
  float sc = __builtin_bit_cast(float, (unsigned)(127 - s) << 23);  // 2^-s
  b = (b - I4 * m) * sc;
  half4_t bh = to_h(b);
  floatx4 zero = {0.f, 0.f, 0.f, 0.f};
  floatx4 a2 = __builtin_amdgcn_mfma_f32_16x16x16f16(bh, bh, zero, 0, 0, 0);
  // deg-4 Taylor: I + b + a2*(I/2 + b/6 + a2/24)
  floatx4 t = I4 * 0.5f + b * (1.f / 6.f) + a2 * (1.f / 24.f);
  floatx4 p = __builtin_amdgcn_mfma_f32_16x16x16f16(to_h(a2), to_h(t), I4 + b,
                                                    0, 0, 0);
  for (int k = 0; k < s; ++k) {
    half4_t ph = to_h(p);
    p = __builtin_amdgcn_mfma_f32_16x16x16f16(ph, ph, zero, 0, 0, 0);
  }
  return p;
}

// ------------------------------------------------------------------
// Kernel E: out = normalize_F( expm( expm(2Q)/2 ) )   [eigh-free identity]
// One wave per matrix: 65536 waves -> full latency hiding.
// ------------------------------------------------------------------
__global__ __launch_bounds__(256) void expm_kernel(
    const f16* __restrict__ ldata, float* __restrict__ out) {
  const int lane = threadIdx.x & 63;
  const int mat = (int)((blockIdx.x * 256u + threadIdx.x) >> 6);
  const int r = lane & 15, q = lane >> 4;
  const f16* ld = ldata + (size_t)mat * 136;

  floatx4 b, I4;
#pragma unroll
  for (int i = 0; i < 4; ++i) {
    int k = q * 4 + i;
    int hi = r > k ? r : k;
    int lo = r + k - hi;
    float v = (float)ld[hi * (hi + 1) / 2 + lo];  // tril row-major index
    bool d = (r == k);
    I4[i] = d ? 1.f : 0.f;
    b[i] = d ? 4.f * v : 2.f * v;  // b = 2*Q (Q diag = 2*ldata)
  }

  // expm #1: p = expm(2Q - m1 I);  Z/2 = e^{m1}/2 * p (exact algebra)
  float m1;
  floatx4 p = expm_c(b, I4, m1);
  float fac = __builtin_amdgcn_exp2f(m1 * 1.4426950408889634f - 1.0f);
  // expm #2: shift constant cancels in the final Frobenius normalization
  float m2;
  p = expm_c(p * fac, I4, m2);

  float n2 = wsum(p[0] * p[0] + p[1] * p[1] + p[2] * p[2] + p[3] * p[3]);
  float inv = __builtin_amdgcn_rsqf(n2);
  floatx4 o = p * inv;
  // value_i = M[r][4q+i] -> out[mat*256 + r*16 + 4q + i]
  *(floatx4*)(out + (size_t)mat * 256 + r * 16 + q * 4) = o;
}

// ------------------------------------------------------------------
extern "C" void kernel_launch(void* const* d_in, const int* in_sizes, int n_in,
                              void* d_out, int out_size, void* d_ws,
                              size_t ws_size, hipStream_t stream) {
  const float* x = (const float*)d_in[0];
  const float* W1 = (const float*)d_in[1];
  const float* b1 = (const float*)d_in[2];
  const float* W2 = (const float*)d_in[3];
  const float* b2 = (const float*)d_in[4];
  const float* W3 = (const float*)d_in[5];
  const float* b3 = (const float*)d_in[6];
  float* out = (float*)d_out;
  f16* wt = (f16*)d_ws;
  f16* ldata = (f16*)((char*)d_ws + LDATA_OFF_BYTES);

  prep_weights<<<168, 256, 0, stream>>>(W1, W2, W3, wt);
  mlp_kernel<<<4096, 256, 0, stream>>>(x, b1, b2, b3, wt, ldata);
  expm_kernel<<<16384, 256, 0, stream>>>(ldata, out);
}

// Round 6
// 130.941 us; speedup vs baseline: 1.1837x; 1.1837x over previous
//
#include <hip/hip_runtime.h>
#include <math.h>

typedef _Float16 f16;
typedef _Float16 half4_t __attribute__((ext_vector_type(4)));
typedef _Float16 half8_t __attribute__((ext_vector_type(8)));
typedef float floatx4 __attribute__((ext_vector_type(4)));

#define LDATA_OFF_BYTES 86016  // after W1t(16384B) + W2t(32768B) + W3t(36864B)

// ------------------------------------------------------------------
// Kernel P: repack weights fp32 -> f16, transposed [col][k] so B-operand
// fragments (k-chunks of 8) are contiguous 16B loads.
// ------------------------------------------------------------------
__global__ __launch_bounds__(256) void prep_weights(
    const float* __restrict__ W1, const float* __restrict__ W2,
    const float* __restrict__ W3, f16* __restrict__ wt) {
  int t = blockIdx.x * 256 + threadIdx.x;
  if (t < 8192) {                       // W1t [128][64]
    int c = t >> 6, k = t & 63;
    wt[t] = (f16)W1[k * 128 + c];
  } else if (t < 24576) {               // W2t [128][128]
    int u = t - 8192;
    int c = u >> 7, k = u & 127;
    wt[t] = (f16)W2[k * 128 + c];
  } else if (t < 43008) {               // W3t [144][128], cols 136..143 zero
    int u = t - 24576;
    int c = u >> 7, k = u & 127;
    wt[t] = (f16)((c < 136) ? W3[k * 136 + c] : 0.0f);
  }
}

// fast tanh: tanh(x) = 1 - 2/(e^{2x}+1)
__device__ __forceinline__ float fast_tanh(float v) {
  float e = __builtin_amdgcn_exp2f(v * 2.885390081777926814f);  // 2*log2(e)
  return 1.0f - 2.0f * __builtin_amdgcn_rcpf(e + 1.0f);
}

// ------------------------------------------------------------------
// Kernel M: weight-RESIDENT 3-layer MLP. 1 wave per block; W2+W3 B-fragments
// preloaded into 272 VGPRs once, then 4 row-tiles of 16 rows stream through
// with zero weight memory traffic (W1, 16KB, stays L1-hot). Activation
// transpose via 4KB XOR-swizzled per-block LDS (conflict-free, in-order DS
// pipe replaces barriers). 1024 blocks = 4 blocks/CU co-resident, one pass.
// ------------------------------------------------------------------
__global__ __launch_bounds__(64, 1) void mlp_kernel(
    const float* __restrict__ x, const float* __restrict__ b1,
    const float* __restrict__ b2v, const float* __restrict__ b3,
    const f16* __restrict__ wt, f16* __restrict__ ldata) {
  __shared__ f16 act[2048];  // 16 rows x 128 cols, 8-f16 groups XOR-swizzled
  const int lane = threadIdx.x & 63;
  const int cl = lane & 15;  // A-row / C-col index
  const int q = lane >> 4;   // quad: k-chunk / C-row-group
  const f16* w1t = wt;           // [128][64]
  const f16* w2t = wt + 8192;    // [128][128]
  const f16* w3t = wt + 24576;   // [144][128]

  // ---- one-time: W2/W3 fragments -> registers (272 VGPR) + biases ----
  half8_t w2f[32], w3f[36];
#pragma unroll
  for (int c8 = 0; c8 < 8; ++c8) {
    int c = c8 * 16 + cl;
#pragma unroll
    for (int ks = 0; ks < 4; ++ks)
      w2f[c8 * 4 + ks] = *(const half8_t*)(w2t + c * 128 + ks * 32 + q * 8);
  }
#pragma unroll
  for (int c8 = 0; c8 < 9; ++c8) {
    int c = c8 * 16 + cl;
#pragma unroll
    for (int ks = 0; ks < 4; ++ks)
      w3f[c8 * 4 + ks] = *(const half8_t*)(w3t + c * 128 + ks * 32 + q * 8);
  }
  float bb1[8], bb2[8], bb3[9];
#pragma unroll
  for (int c8 = 0; c8 < 8; ++c8) {
    bb1[c8] = b1[c8 * 16 + cl];
    bb2[c8] = b2v[c8 * 16 + cl];
    bb3[c8] = b3[c8 * 16 + cl];
  }
  bb3[8] = (cl < 8) ? b3[128 + cl] : 0.f;

  const int tile0 = blockIdx.x * 4;
  // prefetch tile 0's x rows
  const float* xp = x + (size_t)(tile0 * 16 + cl) * 64 + q * 8;
  floatx4 v0 = *(const floatx4*)xp;
  floatx4 v1 = *(const floatx4*)(xp + 4);
  floatx4 v2 = *(const floatx4*)(xp + 32);
  floatx4 v3 = *(const floatx4*)(xp + 36);

  for (int t = 0; t < 4; ++t) {
    const int r0 = (tile0 + t) * 16;
    // convert current x, then prefetch next tile's x (hide HBM latency)
    half8_t a0, a1;
#pragma unroll
    for (int i = 0; i < 4; ++i) {
      a0[i] = (f16)v0[i]; a0[i + 4] = (f16)v1[i];
      a1[i] = (f16)v2[i]; a1[i + 4] = (f16)v3[i];
    }
    if (t < 3) {
      xp = x + (size_t)((tile0 + t + 1) * 16 + cl) * 64 + q * 8;
      v0 = *(const floatx4*)xp;
      v1 = *(const floatx4*)(xp + 4);
      v2 = *(const floatx4*)(xp + 32);
      v3 = *(const floatx4*)(xp + 36);
    }

    // ---- Layer 1: [16x64] @ [64x128] (W1 from global, L1-hot) ----
#pragma unroll
    for (int c8 = 0; c8 < 8; ++c8) {
      int c = c8 * 16 + cl;
      half8_t u0 = *(const half8_t*)(w1t + c * 64 + q * 8);
      half8_t u1 = *(const half8_t*)(w1t + c * 64 + 32 + q * 8);
      floatx4 acc = {0.f, 0.f, 0.f, 0.f};
      acc = __builtin_amdgcn_mfma_f32_16x16x32_f16(a0, u0, acc, 0, 0, 0);
      acc = __builtin_amdgcn_mfma_f32_16x16x32_f16(a1, u1, acc, 0, 0, 0);
#pragma unroll
      for (int i = 0; i < 4; ++i) {
        float v = acc[i] + bb1[c8];
        v = v > 0.f ? v : 0.01f * v;  // LeakyReLU
        int row = q * 4 + i;
        int gs = ((c8 * 2 + (cl >> 3)) ^ row) & 15;  // XOR-swizzled group
        act[row * 128 + gs * 8 + (cl & 7)] = (f16)v;
      }
    }

    // A-fragments of h1 (in-order DS pipe: reads see the writes above)
    half8_t ha[4];
#pragma unroll
    for (int ks = 0; ks < 4; ++ks)
      ha[ks] = *(const half8_t*)(act + cl * 128 +
                                 ((((ks << 2) | q) ^ (cl & 15)) << 3));

    // ---- Layer 2: [16x128] @ [128x128] (weights in VGPRs) ----
#pragma unroll
    for (int c8 = 0; c8 < 8; ++c8) {
      floatx4 acc = {0.f, 0.f, 0.f, 0.f};
#pragma unroll
      for (int ks = 0; ks < 4; ++ks)
        acc = __builtin_amdgcn_mfma_f32_16x16x32_f16(ha[ks], w2f[c8 * 4 + ks],
                                                     acc, 0, 0, 0);
      int c = c8 * 16 + cl;
#pragma unroll
      for (int i = 0; i < 4; ++i) {
        float v = acc[i] + bb2[c8];
        v = v > 0.f ? v : 0.01f * v;
        int row = q * 4 + i;
        int gs = ((c8 * 2 + (cl >> 3)) ^ row) & 15;
        act[row * 128 + gs * 8 + (cl & 7)] = (f16)v;
      }
    }

#pragma unroll
    for (int ks = 0; ks < 4; ++ks)
      ha[ks] = *(const half8_t*)(act + cl * 128 +
                                 ((((ks << 2) | q) ^ (cl & 15)) << 3));

    // ---- Layer 3: [16x128] @ [128x136] + tanh (weights in VGPRs) ----
#pragma unroll
    for (int c8 = 0; c8 < 9; ++c8) {
      floatx4 acc = {0.f, 0.f, 0.f, 0.f};
#pragma unroll
      for (int ks = 0; ks < 4; ++ks)
        acc = __builtin_amdgcn_mfma_f32_16x16x32_f16(ha[ks], w3f[c8 * 4 + ks],
                                                     acc, 0, 0, 0);
      int c = c8 * 16 + cl;
      if (c < 136) {
#pragma unroll
        for (int i = 0; i < 4; ++i)
          ldata[(size_t)(r0 + q * 4 + i) * 136 + c] =
              (f16)fast_tanh(acc[i] + bb3[c8]);
      }
    }
  }
}

// ---- DPP wave64 sum: row_shr 1/2/4/8 then row_bcast 15/31; total in lane 63.
template <int CTRL>
__device__ __forceinline__ float dpp_add(float v) {
  int t = __builtin_amdgcn_update_dpp(0, __builtin_bit_cast(int, v), CTRL,
                                      0xf, 0xf, true);
  return v + __builtin_bit_cast(float, t);
}
__device__ __forceinline__ float wsum(float v) {
  v = dpp_add<0x111>(v);  // row_shr:1
  v = dpp_add<0x112>(v);  // row_shr:2
  v = dpp_add<0x114>(v);  // row_shr:4
  v = dpp_add<0x118>(v);  // row_shr:8
  v = dpp_add<0x142>(v);  // row_bcast:15
  v = dpp_add<0x143>(v);  // row_bcast:31
  return __builtin_bit_cast(
      float, __builtin_amdgcn_readlane(__builtin_bit_cast(int, v), 63));
}

// round floatx4 -> half4 via packed RTZ converts
__device__ __forceinline__ half4_t to_h(floatx4 v) {
  auto p0 = __builtin_amdgcn_cvt_pkrtz(v[0], v[1]);
  auto p1 = __builtin_amdgcn_cvt_pkrtz(v[2], v[3]);
  half4_t h;
  h[0] = p0[0]; h[1] = p0[1]; h[2] = p1[0]; h[3] = p1[1];
  return h;
}

// ------------------------------------------------------------------
// p = expm(B - m I), m = trace/16. Canonical symmetric fragment layout:
// lane value_i = X[l&15][4*(l>>4)+i] is simultaneously a valid A, B and C/D
// layout for v_mfma_f32_16x16x16_f16 (polynomials of a symmetric matrix stay
// symmetric -> zero cross-lane data movement). Degree-4 Paterson-Stockmeyer,
// spectral bound theta <= 0.354 via Frobenius power-of-2 scaling.
// ------------------------------------------------------------------
__device__ __forceinline__ floatx4 expm_c(floatx4 b, floatx4 I4, float& m) {
  float s2 = wsum(b[0] * b[0] + b[1] * b[1] + b[2] * b[2] + b[3] * b[3]);
  float td = wsum(I4[0] * b[0] + I4[1] * b[1] + I4[2] * b[2] + I4[3] * b[3]);
  m = td * 0.0625f;
  float fr2 = fmaxf(s2 - td * m, 1e-30f);  // ||B - mI||_F^2
  int e2 = (int)(__builtin_bit_cast(unsigned, fr2) >> 23) - 127;
  int s = (e2 + 5) >> 1;  // guarantees 2^-s * fr <= 2^-1.5 = 0.354
  s = s < 0 ? 0 : (s > 12 ? 12 : s);
  s = __builtin_amdgcn_readfirstlane(s);
  float sc = __builtin_bit_cast(float, (unsigned)(127 - s) << 23);  // 2^-s
  b = (b - I4 * m) * sc;
  half4_t bh = to_h(b);
  floatx4 zero = {0.f, 0.f, 0.f, 0.f};
  floatx4 a2 = __builtin_amdgcn_mfma_f32_16x16x16f16(bh, bh, zero, 0, 0, 0);
  // deg-4 Taylor: I + b + a2*(I/2 + b/6 + a2/24)
  floatx4 t = I4 * 0.5f + b * (1.f / 6.f) + a2 * (1.f / 24.f);
  floatx4 p = __builtin_amdgcn_mfma_f32_16x16x16f16(to_h(a2), to_h(t), I4 + b,
                                                    0, 0, 0);
  for (int k = 0; k < s; ++k) {
    half4_t ph = to_h(p);
    p = __builtin_amdgcn_mfma_f32_16x16x16f16(ph, ph, zero, 0, 0, 0);
  }
  return p;
}

// ------------------------------------------------------------------
// Kernel E: out = normalize_F( expm( expm(2Q)/2 ) )   [eigh-free identity]
// One wave per matrix: 65536 waves -> full latency hiding.
// ------------------------------------------------------------------
__global__ __launch_bounds__(256) void expm_kernel(
    const f16* __restrict__ ldata, float* __restrict__ out) {
  const int lane = threadIdx.x & 63;
  const int mat = (int)((blockIdx.x * 256u + threadIdx.x) >> 6);
  const int r = lane & 15, q = lane >> 4;
  const f16* ld = ldata + (size_t)mat * 136;

  floatx4 b, I4;
#pragma unroll
  for (int i = 0; i < 4; ++i) {
    int k = q * 4 + i;
    int hi = r > k ? r : k;
    int lo = r + k - hi;
    float v = (float)ld[hi * (hi + 1) / 2 + lo];  // tril row-major index
    bool d = (r == k);
    I4[i] = d ? 1.f : 0.f;
    b[i] = d ? 4.f * v : 2.f * v;  // b = 2*Q (Q diag = 2*ldata)
  }

  // expm #1: p = expm(2Q - m1 I);  Z/2 = e^{m1}/2 * p (exact algebra)
  float m1;
  floatx4 p = expm_c(b, I4, m1);
  float fac = __builtin_amdgcn_exp2f(m1 * 1.4426950408889634f - 1.0f);
  // expm #2: shift constant cancels in the final Frobenius normalization
  float m2;
  p = expm_c(p * fac, I4, m2);

  float n2 = wsum(p[0] * p[0] + p[1] * p[1] + p[2] * p[2] + p[3] * p[3]);
  float inv = __builtin_amdgcn_rsqf(n2);
  floatx4 o = p * inv;
  // value_i = M[r][4q+i] -> out[mat*256 + r*16 + 4q + i]
  *(floatx4*)(out + (size_t)mat * 256 + r * 16 + q * 4) = o;
}

// ------------------------------------------------------------------
extern "C" void kernel_launch(void* const* d_in, const int* in_sizes, int n_in,
                              void* d_out, int out_size, void* d_ws,
                              size_t ws_size, hipStream_t stream) {
  const float* x = (const float*)d_in[0];
  const float* W1 = (const float*)d_in[1];
  const float* b1 = (const float*)d_in[2];
  const float* W2 = (const float*)d_in[3];
  const float* b2 = (const float*)d_in[4];
  const float* W3 = (const float*)d_in[5];
  const float* b3 = (const float*)d_in[6];
  float* out = (float*)d_out;
  f16* wt = (f16*)d_ws;
  f16* ldata = (f16*)((char*)d_ws + LDATA_OFF_BYTES);

  prep_weights<<<168, 256, 0, stream>>>(W1, W2, W3, wt);
  mlp_kernel<<<1024, 64, 0, stream>>>(x, b1, b2, b3, wt, ldata);
  expm_kernel<<<16384, 256, 0, stream>>>(ldata, out);
}